// Round 2
// baseline (467.450 us; speedup 1.0000x reference)
//
#include <hip/hip_runtime.h>

// Problem constants (B, T, IN, H, OUT) = (256, 128, 128, 256, 128)
// All external tensors are float32 (per reference). Internal MFMA compute in
// bf16 with f32 accumulate; internal gx workspace stored bf16.
#define B_   256
#define T_   128
#define IN_  128
#define H_   256
#define H3_  768
#define OUT_ 128

typedef unsigned short u16;
typedef u16   u16x4  __attribute__((ext_vector_type(4)));
typedef u16   u16x8  __attribute__((ext_vector_type(8)));
typedef __bf16 bf16x8 __attribute__((ext_vector_type(8)));
typedef float f32x4  __attribute__((ext_vector_type(4)));

__device__ __forceinline__ float bf2f(u16 u) {
  unsigned int v = ((unsigned int)u) << 16;
  return __builtin_bit_cast(float, v);
}
__device__ __forceinline__ u16 f2bf(float f) {
  unsigned int u = __builtin_bit_cast(unsigned int, f);
  u += 0x7fffu + ((u >> 16) & 1u);   // RNE
  return (u16)(u >> 16);
}
__device__ __forceinline__ f32x4 mfma16(bf16x8 a, bf16x8 b, f32x4 c) {
  return __builtin_amdgcn_mfma_f32_16x16x32_bf16(a, b, c, 0, 0, 0);
}

// ---------------------------------------------------------------------------
// Kernel 1: Wx (f32, 128 x 768) -> WxT (bf16, 768 x 128)
__global__ __launch_bounds__(256) void wx_transpose(const float* __restrict__ Wx,
                                                    u16* __restrict__ WxT) {
  int o = blockIdx.x * 256 + threadIdx.x;       // 0..98303
  int n = o >> 7, k = o & 127;
  WxT[o] = f2bf(Wx[(size_t)k * H3_ + n]);
}

// ---------------------------------------------------------------------------
// Kernel 2: gx[t*B + b][n] = bf16( x[b,t,:] @ Wx[:,n] + bx[n] + (n<512 ? bh[n] : 0) )
// M=32768 (m = t*256 + b), N=768, K=128. Tile: 128(M) x 64(N), full K.
__global__ __launch_bounds__(256) void gx_gemm(const float* __restrict__ x,
                                               const u16* __restrict__ WxT,
                                               const float* __restrict__ bx,
                                               const float* __restrict__ bh,
                                               u16* __restrict__ gxw) {
  __shared__ __align__(16) u16 As[128][136];  // +8 pad: conflict-free b128 frag reads
  __shared__ __align__(16) u16 Bs[64][136];
  const int mt = blockIdx.x;                  // 0..255
  const int n0 = blockIdx.y * 64;             // 0..704
  const int m0 = mt * 128;
  const int t  = mt >> 1;
  const int brow0 = (mt & 1) * 128;
  const int tid = threadIdx.x;
  const int w = tid >> 6, lane = tid & 63, quad = lane >> 4, r = lane & 15;

  {  // A tile: row m0+row == (t*256 + brow0+row); convert f32 -> bf16 in staging
    int row = tid >> 1;
    int colc = (tid & 1) * 64;
    const float* s = x + ((size_t)(brow0 + row) * T_ + t) * IN_ + colc;
    #pragma unroll
    for (int c4 = 0; c4 < 16; ++c4) {
      f32x4 v = *(const f32x4*)(s + c4 * 4);
      u16x4 b;
      b[0] = f2bf(v[0]); b[1] = f2bf(v[1]); b[2] = f2bf(v[2]); b[3] = f2bf(v[3]);
      *(u16x4*)&As[row][colc + c4 * 4] = b;
    }
  }
  {  // B tile (transposed layout [n][k]) from WxT (already bf16)
    int row = tid >> 2;
    int colc = (tid & 3) * 32;
    const u16* s = WxT + (size_t)(n0 + row) * IN_ + colc;
    #pragma unroll
    for (int cch = 0; cch < 4; ++cch)
      *(u16x8*)&Bs[row][colc + cch * 8] = *(const u16x8*)(s + cch * 8);
  }
  __syncthreads();

  f32x4 acc[2][4];
  #pragma unroll
  for (int i = 0; i < 2; ++i)
    #pragma unroll
    for (int j = 0; j < 4; ++j)
      acc[i][j] = (f32x4){0.f, 0.f, 0.f, 0.f};

  #pragma unroll
  for (int kk = 0; kk < 4; ++kk) {
    bf16x8 a0 = *(const bf16x8*)&As[w * 32 + r][kk * 32 + quad * 8];
    bf16x8 a1 = *(const bf16x8*)&As[w * 32 + 16 + r][kk * 32 + quad * 8];
    #pragma unroll
    for (int nt2 = 0; nt2 < 4; ++nt2) {
      bf16x8 b = *(const bf16x8*)&Bs[nt2 * 16 + r][kk * 32 + quad * 8];
      acc[0][nt2] = mfma16(a0, b, acc[0][nt2]);
      acc[1][nt2] = mfma16(a1, b, acc[1][nt2]);
    }
  }

  #pragma unroll
  for (int mt2 = 0; mt2 < 2; ++mt2)
    #pragma unroll
    for (int nt2 = 0; nt2 < 4; ++nt2) {
      int n = n0 + nt2 * 16 + r;                       // C col = lane&15
      float bias = bx[n] + (n < 512 ? bh[n] : 0.f);
      #pragma unroll
      for (int e = 0; e < 4; ++e) {                    // C row = quad*4 + e
        int mrow = w * 32 + mt2 * 16 + quad * 4 + e;
        gxw[(size_t)(m0 + mrow) * H3_ + n] = f2bf(acc[mt2][nt2][e] + bias);
      }
    }
}

// ---------------------------------------------------------------------------
// Kernel 3: the scan. 48 blocks x 512 threads. Block (c, b-group of 16) owns
// 16 independent rows; full Wh held as per-lane MFMA B-fragments (192 VGPRs).
// h kept in LDS: bf16 copy (MFMA A) + f32 master (precision).
__global__ __launch_bounds__(512) void cru_scan(const float* __restrict__ hid,
                                                const float* __restrict__ Wh,
                                                const float* __restrict__ bh,
                                                const u16* __restrict__ gx,
                                                float* __restrict__ hT) {
  __shared__ __align__(16) u16  h_bf[16][264];   // +8 pad -> 2-way (free) frag reads
  __shared__ float h_f[16][257];
  __shared__ __align__(16) u16  gx_s[16][776];   // staged gx tile for this step

  const int bid = blockIdx.x;
  const int c   = bid >> 4;
  const int b0  = (bid & 15) << 4;
  const int tid = threadIdx.x;
  const int w = tid >> 6, lane = tid & 63, quad = lane >> 4, r = lane & 15;

  for (int idx = tid; idx < 16 * 256; idx += 512) {
    int m = idx >> 8, j = idx & 255;
    float hv = hid[((size_t)(c * 256 + b0 + m)) * 256 + j];
    h_f[m][j] = hv;
    h_bf[m][j] = f2bf(hv);
  }

  // One-time B-fragment gather: wave w owns cols {g*256 + w*32 + s*16 + r}.
  // b[j] = Wh[k = kk*32 + quad*8 + j][n]  (f32 source -> bf16 frags)
  bf16x8 bfr[3][2][8];
  #pragma unroll
  for (int g = 0; g < 3; ++g)
    #pragma unroll
    for (int s = 0; s < 2; ++s) {
      const int n = g * 256 + w * 32 + s * 16 + r;
      const float* p = Wh + (size_t)(quad * 8) * H3_ + n;
      #pragma unroll
      for (int kk = 0; kk < 8; ++kk) {
        u16x8 tmp;
        #pragma unroll
        for (int j = 0; j < 8; ++j)
          tmp[j] = f2bf(p[(size_t)(kk * 32 + j) * H3_]);
        bfr[g][s][kk] = __builtin_bit_cast(bf16x8, tmp);
      }
    }

  const float bhn0 = bh[512 + w * 32 + r];        // n-gate bh (not foldable:
  const float bhn1 = bh[512 + w * 32 + 16 + r];   // it is multiplied by r)

  __syncthreads();

  for (int t = 0; t < T_; ++t) {
    // Issue this step's gx tile loads early; 16 rows x 768 cols contiguous.
    const u16* src = gx + ((size_t)t * 256 + b0) * H3_;
    u16x8 st[3];
    int row_[3], off_[3];
    #pragma unroll
    for (int it = 0; it < 3; ++it) {
      int chunk = tid + it * 512;        // 1536 chunks of 8 elems
      int row = chunk / 96;
      int off = (chunk % 96) * 8;
      row_[it] = row; off_[it] = off;
      st[it] = *(const u16x8*)(src + (size_t)row * H3_ + off);
    }

    f32x4 acc[3][2];
    #pragma unroll
    for (int g = 0; g < 3; ++g)
      #pragma unroll
      for (int s = 0; s < 2; ++s)
        acc[g][s] = (f32x4){0.f, 0.f, 0.f, 0.f};

    #pragma unroll
    for (int kk = 0; kk < 8; ++kk) {
      bf16x8 a = *(const bf16x8*)&h_bf[r][kk * 32 + quad * 8];  // A[m=lane&15][k]
      #pragma unroll
      for (int g = 0; g < 3; ++g)
        #pragma unroll
        for (int s = 0; s < 2; ++s)
          acc[g][s] = mfma16(a, bfr[g][s][kk], acc[g][s]);
    }

    #pragma unroll
    for (int it = 0; it < 3; ++it)
      *(u16x8*)&gx_s[row_[it]][off_[it]] = st[it];

    __syncthreads();  // all A-reads done; gx tile staged for everyone

    #pragma unroll
    for (int s = 0; s < 2; ++s) {
      const int j = w * 32 + s * 16 + r;
      const float bhn = s ? bhn1 : bhn0;
      #pragma unroll
      for (int e = 0; e < 4; ++e) {
        const int m = quad * 4 + e;                    // C row = quad*4 + e
        float xr = bf2f(gx_s[m][j]);
        float xz = bf2f(gx_s[m][256 + j]);
        float xn = bf2f(gx_s[m][512 + j]);
        float rr = xr + acc[0][s][e];
        rr = __builtin_amdgcn_rcpf(1.f + __expf(-rr));
        float zz = xz + acc[1][s][e];
        zz = __builtin_amdgcn_rcpf(1.f + __expf(-zz));
        float nv = xn + rr * (acc[2][s][e] + bhn);
        nv = fminf(fmaxf(nv, -15.f), 15.f);
        float tt = __expf(-2.f * nv);
        float nn = (1.f - tt) * __builtin_amdgcn_rcpf(1.f + tt);
        float ho = h_f[m][j];
        float hv = nn + zz * (ho - nn);
        h_f[m][j] = hv;
        h_bf[m][j] = f2bf(hv);
      }
    }
    __syncthreads();  // h ready for next step's A-frag reads
  }

  for (int idx = tid; idx < 16 * 256; idx += 512) {
    int m = idx >> 8, j = idx & 255;
    hT[((size_t)(c * 256 + b0 + m)) * 256 + j] = h_f[m][j];
  }
}

// ---------------------------------------------------------------------------
// Kernel 4: out[b] = elu(sum_c hT[c,b,:] @ Wf + bf); feature[c,:] = mean_b hT
__global__ __launch_bounds__(128) void finalize(const float* __restrict__ hT,
                                                const float* __restrict__ Wf,
                                                const float* __restrict__ bfv,
                                                float* __restrict__ out) {
  __shared__ float hsum[256];
  const int bid = blockIdx.x, tid = threadIdx.x;
  if (bid < 256) {
    const int b = bid;
    for (int k = tid; k < 256; k += 128)
      hsum[k] = hT[((size_t)(0 * 256 + b)) * 256 + k]
              + hT[((size_t)(1 * 256 + b)) * 256 + k]
              + hT[((size_t)(2 * 256 + b)) * 256 + k];
    __syncthreads();
    float acc = bfv[tid];
    #pragma unroll 8
    for (int k = 0; k < 256; ++k)
      acc = fmaf(hsum[k], Wf[(size_t)k * OUT_ + tid], acc);
    float rv = acc > 0.f ? acc : (__expf(acc) - 1.f);
    out[b * OUT_ + tid] = rv;
  } else {
    const int idx = bid - 256;                 // 0..5
    const int c = idx >> 1, j = ((idx & 1) << 7) + tid;
    float sum = 0.f;
    #pragma unroll 4
    for (int b = 0; b < 256; ++b)
      sum += hT[((size_t)(c * 256 + b)) * 256 + j];
    out[B_ * OUT_ + c * 256 + j] = sum * (1.f / 256.f);
  }
}

// ---------------------------------------------------------------------------
extern "C" void kernel_launch(void* const* d_in, const int* in_sizes, int n_in,
                              void* d_out, int out_size, void* d_ws, size_t ws_size,
                              hipStream_t stream) {
  const float* x   = (const float*)d_in[0];
  const float* hid = (const float*)d_in[1];
  const float* Wx  = (const float*)d_in[2];
  const float* bx  = (const float*)d_in[3];
  const float* Wh  = (const float*)d_in[4];
  const float* bh  = (const float*)d_in[5];
  const float* Wf  = (const float*)d_in[6];
  const float* bf_ = (const float*)d_in[7];
  float* out = (float*)d_out;

  char* ws = (char*)d_ws;
  u16* WxT   = (u16*)ws;                                   // 768*128 bf16 = 192 KiB
  u16* gxw   = (u16*)(ws + (1 << 18));                     // 128*256*768 bf16 = 48 MiB
  float* hTw = (float*)(ws + (1 << 18) + (size_t)T_ * B_ * H3_ * 2);  // 3*256*256 f32

  wx_transpose<<<384, 256, 0, stream>>>(Wx, WxT);
  gx_gemm<<<dim3(256, 12), 256, 0, stream>>>(x, WxT, bx, bh, gxw);
  cru_scan<<<48, 512, 0, stream>>>(hid, Wh, bh, gxw, hTw);
  finalize<<<262, 128, 0, stream>>>(hTw, Wf, bf_, out);
}

// Round 3
// 427.368 us; speedup vs baseline: 1.0938x; 1.0938x over previous
//
#include <hip/hip_runtime.h>

// Problem constants (B, T, IN, H, OUT) = (256, 128, 128, 256, 128)
// All external tensors are float32 (per reference). Internal MFMA compute in
// bf16 with f32 accumulate; internal gx workspace stored bf16.
#define B_   256
#define T_   128
#define IN_  128
#define H_   256
#define H3_  768
#define OUT_ 128

typedef unsigned short u16;
typedef u16   u16x4  __attribute__((ext_vector_type(4)));
typedef u16   u16x8  __attribute__((ext_vector_type(8)));
typedef __bf16 bf16x8 __attribute__((ext_vector_type(8)));
typedef float f32x4  __attribute__((ext_vector_type(4)));

__device__ __forceinline__ float bf2f(u16 u) {
  unsigned int v = ((unsigned int)u) << 16;
  return __builtin_bit_cast(float, v);
}
__device__ __forceinline__ u16 f2bf(float f) {        // RNE (used off hot path)
  unsigned int u = __builtin_bit_cast(unsigned int, f);
  u += 0x7fffu + ((u >> 16) & 1u);
  return (u16)(u >> 16);
}
__device__ __forceinline__ u16 f2bf_fast(float f) {   // round-half-up, 2 instrs
  unsigned int u = __builtin_bit_cast(unsigned int, f);
  return (u16)((u + 0x8000u) >> 16);
}
__device__ __forceinline__ f32x4 mfma16(bf16x8 a, bf16x8 b, f32x4 c) {
  return __builtin_amdgcn_mfma_f32_16x16x32_bf16(a, b, c, 0, 0, 0);
}

// ---------------------------------------------------------------------------
// Kernel 1: Wx (f32, 128 x 768) -> WxT (bf16, 768 x 128)
__global__ __launch_bounds__(256) void wx_transpose(const float* __restrict__ Wx,
                                                    u16* __restrict__ WxT) {
  int o = blockIdx.x * 256 + threadIdx.x;       // 0..98303
  int n = o >> 7, k = o & 127;
  WxT[o] = f2bf(Wx[(size_t)k * H3_ + n]);
}

// ---------------------------------------------------------------------------
// Kernel 2: gx[t*B + b][n] = bf16( x[b,t,:] @ Wx[:,n] + bx[n] + (n<512 ? bh[n] : 0) )
// M=32768 (m = t*256 + b), N=768, K=128. Tile: 128(M) x 64(N), full K.
__global__ __launch_bounds__(256) void gx_gemm(const float* __restrict__ x,
                                               const u16* __restrict__ WxT,
                                               const float* __restrict__ bx,
                                               const float* __restrict__ bh,
                                               u16* __restrict__ gxw) {
  __shared__ __align__(16) u16 As[128][136];  // +8 pad: conflict-free b128 frag reads
  __shared__ __align__(16) u16 Bs[64][136];
  const int mt = blockIdx.x;                  // 0..255
  const int n0 = blockIdx.y * 64;             // 0..704
  const int m0 = mt * 128;
  const int t  = mt >> 1;
  const int brow0 = (mt & 1) * 128;
  const int tid = threadIdx.x;
  const int w = tid >> 6, lane = tid & 63, quad = lane >> 4, r = lane & 15;

  {  // A tile: row m0+row == (t*256 + brow0+row); convert f32 -> bf16 in staging
    int row = tid >> 1;
    int colc = (tid & 1) * 64;
    const float* s = x + ((size_t)(brow0 + row) * T_ + t) * IN_ + colc;
    #pragma unroll
    for (int c4 = 0; c4 < 16; ++c4) {
      f32x4 v = *(const f32x4*)(s + c4 * 4);
      u16x4 b;
      b[0] = f2bf(v[0]); b[1] = f2bf(v[1]); b[2] = f2bf(v[2]); b[3] = f2bf(v[3]);
      *(u16x4*)&As[row][colc + c4 * 4] = b;
    }
  }
  {  // B tile (transposed layout [n][k]) from WxT (already bf16)
    int row = tid >> 2;
    int colc = (tid & 3) * 32;
    const u16* s = WxT + (size_t)(n0 + row) * IN_ + colc;
    #pragma unroll
    for (int cch = 0; cch < 4; ++cch)
      *(u16x8*)&Bs[row][colc + cch * 8] = *(const u16x8*)(s + cch * 8);
  }
  __syncthreads();

  f32x4 acc[2][4];
  #pragma unroll
  for (int i = 0; i < 2; ++i)
    #pragma unroll
    for (int j = 0; j < 4; ++j)
      acc[i][j] = (f32x4){0.f, 0.f, 0.f, 0.f};

  #pragma unroll
  for (int kk = 0; kk < 4; ++kk) {
    bf16x8 a0 = *(const bf16x8*)&As[w * 32 + r][kk * 32 + quad * 8];
    bf16x8 a1 = *(const bf16x8*)&As[w * 32 + 16 + r][kk * 32 + quad * 8];
    #pragma unroll
    for (int nt2 = 0; nt2 < 4; ++nt2) {
      bf16x8 b = *(const bf16x8*)&Bs[nt2 * 16 + r][kk * 32 + quad * 8];
      acc[0][nt2] = mfma16(a0, b, acc[0][nt2]);
      acc[1][nt2] = mfma16(a1, b, acc[1][nt2]);
    }
  }

  #pragma unroll
  for (int mt2 = 0; mt2 < 2; ++mt2)
    #pragma unroll
    for (int nt2 = 0; nt2 < 4; ++nt2) {
      int n = n0 + nt2 * 16 + r;                       // C col = lane&15
      float bias = bx[n] + (n < 512 ? bh[n] : 0.f);
      #pragma unroll
      for (int e = 0; e < 4; ++e) {                    // C row = quad*4 + e
        int mrow = w * 32 + mt2 * 16 + quad * 4 + e;
        gxw[(size_t)(m0 + mrow) * H3_ + n] = f2bf(acc[mt2][nt2][e] + bias);
      }
    }
}

// ---------------------------------------------------------------------------
// Kernel 3: the scan. 48 blocks x 512 threads. Block (c, b-group of 16) owns
// 16 independent rows; full Wh held as per-lane MFMA B-fragments.
// Round-3 structure:
//   - h_bf double-buffered -> ONE __syncthreads per step
//   - gx prefetched a FULL step ahead (regs across the step, staged to the
//     other gx_s buffer just before the barrier)
//   - f32 h master in registers (thread-private (m,j) map is step-invariant)
__global__ __launch_bounds__(512) void cru_scan(const float* __restrict__ hid,
                                                const float* __restrict__ Wh,
                                                const float* __restrict__ bh,
                                                const u16* __restrict__ gx,
                                                float* __restrict__ hT) {
  __shared__ __align__(16) u16 h_bf[2][16][264];  // +8 pad -> 2-way (free) frag reads
  __shared__ __align__(16) u16 gx_s[2][16][776];  // double-buffered gx tile

  const int bid = blockIdx.x;
  const int c   = bid >> 4;
  const int b0  = (bid & 15) << 4;
  const int tid = threadIdx.x;
  const int w = tid >> 6, lane = tid & 63, quad = lane >> 4, r = lane & 15;

  // gx staging chunk map (constant per thread): 1536 chunks of 8 u16
  int row_[3], off_[3];
  #pragma unroll
  for (int it = 0; it < 3; ++it) {
    int chunk = tid + it * 512;
    row_[it] = chunk / 96;
    off_[it] = (chunk % 96) * 8;
  }

  // init h: cooperative bf16 fill + per-thread f32 master registers
  for (int idx = tid; idx < 16 * 256; idx += 512) {
    int m = idx >> 8, j = idx & 255;
    h_bf[0][m][j] = f2bf(hid[((size_t)(c * 256 + b0 + m)) * 256 + j]);
  }
  float h_reg[2][4];
  #pragma unroll
  for (int s = 0; s < 2; ++s) {
    const int j = w * 32 + s * 16 + r;
    #pragma unroll
    for (int e = 0; e < 4; ++e)
      h_reg[s][e] = hid[((size_t)(c * 256 + b0 + quad * 4 + e)) * 256 + j];
  }

  // preload gx tile for t=0 into gx_s[0]
  {
    const u16* src = gx + (size_t)b0 * H3_;
    #pragma unroll
    for (int it = 0; it < 3; ++it)
      *(u16x8*)&gx_s[0][row_[it]][off_[it]] =
          *(const u16x8*)(src + (size_t)row_[it] * H3_ + off_[it]);
  }

  // One-time B-fragment gather: wave w owns cols {g*256 + w*32 + s*16 + r}.
  // b[j] = Wh[k = kk*32 + quad*8 + j][n]  (f32 source -> bf16 frags)
  bf16x8 bfr[3][2][8];
  #pragma unroll
  for (int g = 0; g < 3; ++g)
    #pragma unroll
    for (int s = 0; s < 2; ++s) {
      const int n = g * 256 + w * 32 + s * 16 + r;
      const float* p = Wh + (size_t)(quad * 8) * H3_ + n;
      #pragma unroll
      for (int kk = 0; kk < 8; ++kk) {
        u16x8 tmp;
        #pragma unroll
        for (int j = 0; j < 8; ++j)
          tmp[j] = f2bf(p[(size_t)(kk * 32 + j) * H3_]);
        bfr[g][s][kk] = __builtin_bit_cast(bf16x8, tmp);
      }
    }

  const float bhn0 = bh[512 + w * 32 + r];        // n-gate bh (not foldable:
  const float bhn1 = bh[512 + w * 32 + 16 + r];   // it is multiplied by r)

  __syncthreads();

  for (int t = 0; t < T_; ++t) {
    const int p = t & 1;

    // A) issue NEXT step's gx loads (held in regs across the whole step)
    const int tn = (t + 1 < T_) ? t + 1 : t;
    const u16* src = gx + ((size_t)tn * 256 + b0) * H3_;
    u16x8 st0 = *(const u16x8*)(src + (size_t)row_[0] * H3_ + off_[0]);
    u16x8 st1 = *(const u16x8*)(src + (size_t)row_[1] * H3_ + off_[1]);
    u16x8 st2 = *(const u16x8*)(src + (size_t)row_[2] * H3_ + off_[2]);

    // B) gh = h @ Wh via MFMA on h_bf[p]
    f32x4 acc[3][2];
    #pragma unroll
    for (int g = 0; g < 3; ++g)
      #pragma unroll
      for (int s = 0; s < 2; ++s)
        acc[g][s] = (f32x4){0.f, 0.f, 0.f, 0.f};

    #pragma unroll
    for (int kk = 0; kk < 8; ++kk) {
      bf16x8 a = *(const bf16x8*)&h_bf[p][r][kk * 32 + quad * 8];  // A[m=lane&15][k]
      #pragma unroll
      for (int g = 0; g < 3; ++g)
        #pragma unroll
        for (int s = 0; s < 2; ++s)
          acc[g][s] = mfma16(a, bfr[g][s][kk], acc[g][s]);
    }

    // C) gate math; reads gx_s[p] (staged last step), writes h_bf[1-p]
    #pragma unroll
    for (int s = 0; s < 2; ++s) {
      const int j = w * 32 + s * 16 + r;
      const float bhn = s ? bhn1 : bhn0;
      #pragma unroll
      for (int e = 0; e < 4; ++e) {
        const int m = quad * 4 + e;                    // C row = quad*4 + e
        float xr = bf2f(gx_s[p][m][j]);
        float xz = bf2f(gx_s[p][m][256 + j]);
        float xn = bf2f(gx_s[p][m][512 + j]);
        float rr = xr + acc[0][s][e];
        rr = __builtin_amdgcn_rcpf(1.f + __expf(-rr));
        float zz = xz + acc[1][s][e];
        zz = __builtin_amdgcn_rcpf(1.f + __expf(-zz));
        float nv = xn + rr * (acc[2][s][e] + bhn);
        nv = fminf(fmaxf(nv, -15.f), 15.f);
        float tt = __expf(-2.f * nv);
        float nn = (1.f - tt) * __builtin_amdgcn_rcpf(1.f + tt);
        float hv = nn + zz * (h_reg[s][e] - nn);
        h_reg[s][e] = hv;
        h_bf[1 - p][m][j] = f2bf_fast(hv);
      }
    }

    // D) stage prefetched gx into the other buffer, then the ONE barrier
    *(u16x8*)&gx_s[1 - p][row_[0]][off_[0]] = st0;
    *(u16x8*)&gx_s[1 - p][row_[1]][off_[1]] = st1;
    *(u16x8*)&gx_s[1 - p][row_[2]][off_[2]] = st2;
    __syncthreads();
  }

  #pragma unroll
  for (int s = 0; s < 2; ++s) {
    const int j = w * 32 + s * 16 + r;
    #pragma unroll
    for (int e = 0; e < 4; ++e)
      hT[((size_t)(c * 256 + b0 + quad * 4 + e)) * 256 + j] = h_reg[s][e];
  }
}

// ---------------------------------------------------------------------------
// Kernel 4: out[b] = elu(sum_c hT[c,b,:] @ Wf + bf); feature[c,:] = mean_b hT
__global__ __launch_bounds__(128) void finalize(const float* __restrict__ hT,
                                                const float* __restrict__ Wf,
                                                const float* __restrict__ bfv,
                                                float* __restrict__ out) {
  __shared__ float hsum[256];
  const int bid = blockIdx.x, tid = threadIdx.x;
  if (bid < 256) {
    const int b = bid;
    for (int k = tid; k < 256; k += 128)
      hsum[k] = hT[((size_t)(0 * 256 + b)) * 256 + k]
              + hT[((size_t)(1 * 256 + b)) * 256 + k]
              + hT[((size_t)(2 * 256 + b)) * 256 + k];
    __syncthreads();
    float acc = bfv[tid];
    #pragma unroll 8
    for (int k = 0; k < 256; ++k)
      acc = fmaf(hsum[k], Wf[(size_t)k * OUT_ + tid], acc);
    float rv = acc > 0.f ? acc : (__expf(acc) - 1.f);
    out[b * OUT_ + tid] = rv;
  } else {
    const int idx = bid - 256;                 // 0..5
    const int c = idx >> 1, j = ((idx & 1) << 7) + tid;
    float sum = 0.f;
    #pragma unroll 4
    for (int b = 0; b < 256; ++b)
      sum += hT[((size_t)(c * 256 + b)) * 256 + j];
    out[B_ * OUT_ + c * 256 + j] = sum * (1.f / 256.f);
  }
}

// ---------------------------------------------------------------------------
extern "C" void kernel_launch(void* const* d_in, const int* in_sizes, int n_in,
                              void* d_out, int out_size, void* d_ws, size_t ws_size,
                              hipStream_t stream) {
  const float* x   = (const float*)d_in[0];
  const float* hid = (const float*)d_in[1];
  const float* Wx  = (const float*)d_in[2];
  const float* bx  = (const float*)d_in[3];
  const float* Wh  = (const float*)d_in[4];
  const float* bh  = (const float*)d_in[5];
  const float* Wf  = (const float*)d_in[6];
  const float* bf_ = (const float*)d_in[7];
  float* out = (float*)d_out;

  char* ws = (char*)d_ws;
  u16* WxT   = (u16*)ws;                                   // 768*128 bf16 = 192 KiB
  u16* gxw   = (u16*)(ws + (1 << 18));                     // 128*256*768 bf16 = 48 MiB
  float* hTw = (float*)(ws + (1 << 18) + (size_t)T_ * B_ * H3_ * 2);  // 3*256*256 f32

  wx_transpose<<<384, 256, 0, stream>>>(Wx, WxT);
  gx_gemm<<<dim3(256, 12), 256, 0, stream>>>(x, WxT, bx, bh, gxw);
  cru_scan<<<48, 512, 0, stream>>>(hid, Wh, bh, gxw, hTw);
  finalize<<<262, 128, 0, stream>>>(hTw, Wf, bf_, out);
}

// Round 4
// 397.319 us; speedup vs baseline: 1.1765x; 1.0756x over previous
//
#include <hip/hip_runtime.h>

// Problem constants (B, T, IN, H, OUT) = (256, 128, 128, 256, 128)
// All external tensors are float32 (per reference). Internal MFMA compute in
// bf16 with f32 accumulate; internal gx workspace stored bf16.
#define B_   256
#define T_   128
#define IN_  128
#define H_   256
#define H3_  768
#define OUT_ 128

typedef unsigned short u16;
typedef u16   u16x4  __attribute__((ext_vector_type(4)));
typedef u16   u16x8  __attribute__((ext_vector_type(8)));
typedef __bf16 bf16x8 __attribute__((ext_vector_type(8)));
typedef float f32x4  __attribute__((ext_vector_type(4)));

__device__ __forceinline__ float bf2f(u16 u) {
  unsigned int v = ((unsigned int)u) << 16;
  return __builtin_bit_cast(float, v);
}
__device__ __forceinline__ u16 f2bf(float f) {        // RNE (off hot path)
  unsigned int u = __builtin_bit_cast(unsigned int, f);
  u += 0x7fffu + ((u >> 16) & 1u);
  return (u16)(u >> 16);
}
__device__ __forceinline__ u16 f2bf_fast(float f) {   // round-half-up, 2 instrs
  unsigned int u = __builtin_bit_cast(unsigned int, f);
  return (u16)((u + 0x8000u) >> 16);
}
__device__ __forceinline__ f32x4 mfma16(bf16x8 a, bf16x8 b, f32x4 c) {
  return __builtin_amdgcn_mfma_f32_16x16x32_bf16(a, b, c, 0, 0, 0);
}

// ---------------------------------------------------------------------------
// Kernel 1: Wx (f32, 128 x 768) -> WxT (bf16, 768 x 128)
__global__ __launch_bounds__(256) void wx_transpose(const float* __restrict__ Wx,
                                                    u16* __restrict__ WxT) {
  int o = blockIdx.x * 256 + threadIdx.x;       // 0..98303
  int n = o >> 7, k = o & 127;
  WxT[o] = f2bf(Wx[(size_t)k * H3_ + n]);
}

// ---------------------------------------------------------------------------
// Kernel 2: gx[t*B + b][n] = bf16( x[b,t,:] @ Wx[:,n] + bx[n] + (n<512 ? bh[n] : 0) )
// M=32768 (m = t*256 + b), N=768, K=128. Tile: 128(M) x 192(N), full K.
// N=192 (vs 64) cuts x re-reads from 12x to 4x (~-60 MB HBM).
__global__ __launch_bounds__(256) void gx_gemm(const float* __restrict__ x,
                                               const u16* __restrict__ WxT,
                                               const float* __restrict__ bx,
                                               const float* __restrict__ bh,
                                               u16* __restrict__ gxw) {
  __shared__ __align__(16) u16 As[128][136];  // 34.8 KB (+8 pad)
  __shared__ __align__(16) u16 Bs[192][136];  // 52.2 KB
  const int mt = blockIdx.x;                  // 0..255
  const int n0 = blockIdx.y * 192;            // 0,192,384,576
  const int m0 = mt * 128;
  const int t  = mt >> 1;
  const int brow0 = (mt & 1) * 128;
  const int tid = threadIdx.x;
  const int w = tid >> 6, lane = tid & 63, quad = lane >> 4, r = lane & 15;

  {  // A tile: row m0+row == (t*256 + brow0+row); convert f32 -> bf16 in staging
    int row = tid >> 1;
    int colc = (tid & 1) * 64;
    const float* s = x + ((size_t)(brow0 + row) * T_ + t) * IN_ + colc;
    #pragma unroll
    for (int c4 = 0; c4 < 16; ++c4) {
      f32x4 v = *(const f32x4*)(s + c4 * 4);
      u16x4 b;
      b[0] = f2bf(v[0]); b[1] = f2bf(v[1]); b[2] = f2bf(v[2]); b[3] = f2bf(v[3]);
      *(u16x4*)&As[row][colc + c4 * 4] = b;
    }
  }
  {  // B tile (transposed layout [n][k]) from WxT (already bf16): 192x128
    for (int i = tid; i < 192 * 16; i += 256) {
      int row = i >> 4, col8 = (i & 15) * 8;
      *(u16x8*)&Bs[row][col8] = *(const u16x8*)(WxT + (size_t)(n0 + row) * IN_ + col8);
    }
  }
  __syncthreads();

  f32x4 acc[2][12];
  #pragma unroll
  for (int i = 0; i < 2; ++i)
    #pragma unroll
    for (int j = 0; j < 12; ++j)
      acc[i][j] = (f32x4){0.f, 0.f, 0.f, 0.f};

  #pragma unroll
  for (int kk = 0; kk < 4; ++kk) {
    bf16x8 a0 = *(const bf16x8*)&As[w * 32 + r][kk * 32 + quad * 8];
    bf16x8 a1 = *(const bf16x8*)&As[w * 32 + 16 + r][kk * 32 + quad * 8];
    #pragma unroll
    for (int nt2 = 0; nt2 < 12; ++nt2) {
      bf16x8 b = *(const bf16x8*)&Bs[nt2 * 16 + r][kk * 32 + quad * 8];
      acc[0][nt2] = mfma16(a0, b, acc[0][nt2]);
      acc[1][nt2] = mfma16(a1, b, acc[1][nt2]);
    }
  }

  #pragma unroll
  for (int mt2 = 0; mt2 < 2; ++mt2)
    #pragma unroll
    for (int nt2 = 0; nt2 < 12; ++nt2) {
      int n = n0 + nt2 * 16 + r;                       // C col = lane&15
      float bias = bx[n] + (n < 512 ? bh[n] : 0.f);
      #pragma unroll
      for (int e = 0; e < 4; ++e) {                    // C row = quad*4 + e
        int mrow = w * 32 + mt2 * 16 + quad * 4 + e;
        gxw[(size_t)(m0 + mrow) * H3_ + n] = f2bf(acc[mt2][nt2][e] + bias);
      }
    }
}

// ---------------------------------------------------------------------------
// Kernel 3: the scan. 48 blocks x 512 threads, 16 rows per block.
// Round-4: TRANSPOSED MFMA (gh^T = Wh^T * h^T, operands swapped). Each thread
// now owns one batch row (m = lane&15) x 4 consecutive H-columns, so:
//   gx reads  : 6 x ds_read_b64   (was 24 x ds_read_u16)
//   h_bf write: 2 x ds_write_b64  (was 8 x ds_write_b16)
//   h_reg / bhn / hid / hT: contiguous f32x4
// Plus: h_bf double-buffered (1 barrier/step), gx prefetched a full step ahead.
__global__ __launch_bounds__(512) void cru_scan(const float* __restrict__ hid,
                                                const float* __restrict__ Wh,
                                                const float* __restrict__ bh,
                                                const u16* __restrict__ gx,
                                                float* __restrict__ hT) {
  __shared__ __align__(16) u16 h_bf[2][16][264];  // +8 pad
  __shared__ __align__(16) u16 gx_s[2][16][776];  // double-buffered gx tile

  const int bid = blockIdx.x;
  const int c   = bid >> 4;
  const int b0  = (bid & 15) << 4;
  const int tid = threadIdx.x;
  const int w = tid >> 6, lane = tid & 63, quad = lane >> 4, r = lane & 15;

  // Thread's H-column bases: jb[s] = w*32 + s*16 + quad*4; batch row m = r.
  const int jb0 = w * 32 + quad * 4;
  const int jb1 = jb0 + 16;

  // gx staging chunk map (constant per thread): 1536 chunks of 8 u16
  int row_[3], off_[3];
  #pragma unroll
  for (int it = 0; it < 3; ++it) {
    int chunk = tid + it * 512;
    row_[it] = chunk / 96;
    off_[it] = (chunk % 96) * 8;
  }

  // init h: cooperative bf16 fill + per-thread f32 master registers
  for (int idx = tid; idx < 16 * 256; idx += 512) {
    int m = idx >> 8, j = idx & 255;
    h_bf[0][m][j] = f2bf(hid[((size_t)(c * 256 + b0 + m)) * 256 + j]);
  }
  f32x4 h_reg[2];
  h_reg[0] = *(const f32x4*)(hid + ((size_t)(c * 256 + b0 + r)) * 256 + jb0);
  h_reg[1] = *(const f32x4*)(hid + ((size_t)(c * 256 + b0 + r)) * 256 + jb1);

  // n-gate bh (not foldable into gx: it is multiplied by r)
  f32x4 bhn[2];
  bhn[0] = *(const f32x4*)(bh + 512 + jb0);
  bhn[1] = *(const f32x4*)(bh + 512 + jb1);

  // preload gx tile for t=0 into gx_s[0]
  {
    const u16* src = gx + (size_t)b0 * H3_;
    #pragma unroll
    for (int it = 0; it < 3; ++it)
      *(u16x8*)&gx_s[0][row_[it]][off_[it]] =
          *(const u16x8*)(src + (size_t)row_[it] * H3_ + off_[it]);
  }

  // One-time Wh^T A-fragment gather (identical gather to the old B-frags):
  // frag[g][s][kk][j] = Wh[kk*32 + quad*8 + j][n], n = g*256 + w*32 + s*16 + r
  bf16x8 bfr[3][2][8];
  #pragma unroll
  for (int g = 0; g < 3; ++g)
    #pragma unroll
    for (int s = 0; s < 2; ++s) {
      const int n = g * 256 + w * 32 + s * 16 + r;
      const float* p = Wh + (size_t)(quad * 8) * H3_ + n;
      #pragma unroll
      for (int kk = 0; kk < 8; ++kk) {
        u16x8 tmp;
        #pragma unroll
        for (int j = 0; j < 8; ++j)
          tmp[j] = f2bf(p[(size_t)(kk * 32 + j) * H3_]);
        bfr[g][s][kk] = __builtin_bit_cast(bf16x8, tmp);
      }
    }

  __syncthreads();

  for (int t = 0; t < T_; ++t) {
    const int p = t & 1;

    // A) issue NEXT step's gx loads (held in regs across the whole step)
    const int tn = (t + 1 < T_) ? t + 1 : t;
    const u16* src = gx + ((size_t)tn * 256 + b0) * H3_;
    u16x8 st0 = *(const u16x8*)(src + (size_t)row_[0] * H3_ + off_[0]);
    u16x8 st1 = *(const u16x8*)(src + (size_t)row_[1] * H3_ + off_[1]);
    u16x8 st2 = *(const u16x8*)(src + (size_t)row_[2] * H3_ + off_[2]);

    // B) gh^T = Wh^T * h^T via MFMA (A = Wh^T frags, B = h frags)
    f32x4 acc[3][2];
    #pragma unroll
    for (int g = 0; g < 3; ++g)
      #pragma unroll
      for (int s = 0; s < 2; ++s)
        acc[g][s] = (f32x4){0.f, 0.f, 0.f, 0.f};

    #pragma unroll
    for (int kk = 0; kk < 8; ++kk) {
      bf16x8 hfrag = *(const bf16x8*)&h_bf[p][r][kk * 32 + quad * 8];  // B[k][m=r]
      #pragma unroll
      for (int g = 0; g < 3; ++g)
        #pragma unroll
        for (int s = 0; s < 2; ++s)
          acc[g][s] = mfma16(bfr[g][s][kk], hfrag, acc[g][s]);
    }

    // C) gate math; D[row=quad*4+e][col=r] = gh[m=r][gcol = g*256 + jb + e]
    #pragma unroll
    for (int s = 0; s < 2; ++s) {
      const int jb = s ? jb1 : jb0;
      u16x4 xr4 = *(const u16x4*)&gx_s[p][r][jb];
      u16x4 xz4 = *(const u16x4*)&gx_s[p][r][256 + jb];
      u16x4 xn4 = *(const u16x4*)&gx_s[p][r][512 + jb];
      u16x4 hw;
      #pragma unroll
      for (int e = 0; e < 4; ++e) {
        float rr = bf2f(xr4[e]) + acc[0][s][e];
        rr = __builtin_amdgcn_rcpf(1.f + __expf(-rr));          // sigmoid (inf-safe)
        float zz = bf2f(xz4[e]) + acc[1][s][e];
        zz = __builtin_amdgcn_rcpf(1.f + __expf(-zz));
        float nv = bf2f(xn4[e]) + rr * (acc[2][s][e] + bhn[s][e]);
        float uu = __builtin_amdgcn_rcpf(1.f + __expf(-2.f * nv));
        float nn = fmaf(2.f, uu, -1.f);                          // tanh, inf-safe
        float hv = nn + zz * (h_reg[s][e] - nn);
        h_reg[s][e] = hv;
        hw[e] = f2bf_fast(hv);
      }
      *(u16x4*)&h_bf[1 - p][r][jb] = hw;                         // one b64 write
    }

    // D) stage prefetched gx into the other buffer, then the ONE barrier
    *(u16x8*)&gx_s[1 - p][row_[0]][off_[0]] = st0;
    *(u16x8*)&gx_s[1 - p][row_[1]][off_[1]] = st1;
    *(u16x8*)&gx_s[1 - p][row_[2]][off_[2]] = st2;
    __syncthreads();
  }

  *(f32x4*)(hT + ((size_t)(c * 256 + b0 + r)) * 256 + jb0) = h_reg[0];
  *(f32x4*)(hT + ((size_t)(c * 256 + b0 + r)) * 256 + jb1) = h_reg[1];
}

// ---------------------------------------------------------------------------
// Kernel 4: out[b] = elu(sum_c hT[c,b,:] @ Wf + bf); feature[c,:] = mean_b hT
__global__ __launch_bounds__(128) void finalize(const float* __restrict__ hT,
                                                const float* __restrict__ Wf,
                                                const float* __restrict__ bfv,
                                                float* __restrict__ out) {
  __shared__ float hsum[256];
  const int bid = blockIdx.x, tid = threadIdx.x;
  if (bid < 256) {
    const int b = bid;
    for (int k = tid; k < 256; k += 128)
      hsum[k] = hT[((size_t)(0 * 256 + b)) * 256 + k]
              + hT[((size_t)(1 * 256 + b)) * 256 + k]
              + hT[((size_t)(2 * 256 + b)) * 256 + k];
    __syncthreads();
    float acc = bfv[tid];
    #pragma unroll 8
    for (int k = 0; k < 256; ++k)
      acc = fmaf(hsum[k], Wf[(size_t)k * OUT_ + tid], acc);
    float rv = acc > 0.f ? acc : (__expf(acc) - 1.f);
    out[b * OUT_ + tid] = rv;
  } else {
    const int idx = bid - 256;                 // 0..5
    const int c = idx >> 1, j = ((idx & 1) << 7) + tid;
    float sum = 0.f;
    #pragma unroll 4
    for (int b = 0; b < 256; ++b)
      sum += hT[((size_t)(c * 256 + b)) * 256 + j];
    out[B_ * OUT_ + c * 256 + j] = sum * (1.f / 256.f);
  }
}

// ---------------------------------------------------------------------------
extern "C" void kernel_launch(void* const* d_in, const int* in_sizes, int n_in,
                              void* d_out, int out_size, void* d_ws, size_t ws_size,
                              hipStream_t stream) {
  const float* x   = (const float*)d_in[0];
  const float* hid = (const float*)d_in[1];
  const float* Wx  = (const float*)d_in[2];
  const float* bx  = (const float*)d_in[3];
  const float* Wh  = (const float*)d_in[4];
  const float* bh  = (const float*)d_in[5];
  const float* Wf  = (const float*)d_in[6];
  const float* bf_ = (const float*)d_in[7];
  float* out = (float*)d_out;

  char* ws = (char*)d_ws;
  u16* WxT   = (u16*)ws;                                   // 768*128 bf16 = 192 KiB
  u16* gxw   = (u16*)(ws + (1 << 18));                     // 128*256*768 bf16 = 48 MiB
  float* hTw = (float*)(ws + (1 << 18) + (size_t)T_ * B_ * H3_ * 2);  // 3*256*256 f32

  wx_transpose<<<384, 256, 0, stream>>>(Wx, WxT);
  gx_gemm<<<dim3(256, 4), 256, 0, stream>>>(x, WxT, bx, bh, gxw);
  cru_scan<<<48, 512, 0, stream>>>(hid, Wh, bh, gxw, hTw);
  finalize<<<262, 128, 0, stream>>>(hTw, Wf, bf_, out);
}